// Round 1
// baseline (821.302 us; speedup 1.0000x reference)
//
#include <hip/hip_runtime.h>

#define NUM_OBJ 256
#define NUM_REL 4096
#define OBJ_DIM 4096
#define REL_DIM 4096
#define HIDDEN 512
#define NUM_OBJ_CLS 151
#define NUM_REL_CLS 51

#define OFF_PREDS (NUM_OBJ * NUM_OBJ_CLS)        // 38656
#define OFF_SOP   (OFF_PREDS + NUM_OBJ)          // 38912
#define OFF_GGNN  (OFF_SOP + NUM_REL * 2)        // 47104

typedef __attribute__((ext_vector_type(4))) float          f32x4;
typedef __attribute__((ext_vector_type(8))) short          bf16x8;
typedef __attribute__((ext_vector_type(4))) unsigned short u16x4;

__device__ __forceinline__ unsigned short f2bf(float f) {
  unsigned int u = __float_as_uint(f);
  u += 0x7FFFu + ((u >> 16) & 1u);   // round-to-nearest-even
  return (unsigned short)(u >> 16);
}

// ---------------- kernel A: logits copy + argmax(preds) ----------------
__global__ __launch_bounds__(64) void preds_kernel(const float* __restrict__ logits,
                                                   float* __restrict__ out) {
  const int row = blockIdx.x;
  const int lane = threadIdx.x;
  const float* lrow = logits + row * NUM_OBJ_CLS;
  float best = -3.0e38f;
  int bidx = NUM_OBJ_CLS;  // sentinel (higher than any real idx)
  for (int j = lane; j < NUM_OBJ_CLS; j += 64) {
    float v = lrow[j];
    out[row * NUM_OBJ_CLS + j] = v;
    if (j >= 1 && v > best) { best = v; bidx = j; }
  }
  // 64-lane butterfly argmax reduce, ties -> lower index (np.argmax semantics)
  for (int off = 1; off < 64; off <<= 1) {
    float ob = __shfl_xor(best, off);
    int   oi = __shfl_xor(bidx, off);
    if (ob > best || (ob == best && oi < bidx)) { best = ob; bidx = oi; }
  }
  if (lane == 0) out[OFF_PREDS + row] = (float)bidx;
}

// ---------------- kernel B/C: C[M][512] = A[M][K] @ W[512][K]^T + bias ----------------
#define BM 128
#define BN 64
#define BK 32
#define LDP 40  // padded LDS K-stride (bf16 elems): 80B rows -> 2-way-max bank aliasing

__global__ __launch_bounds__(256) void gemm_bt_bias(const float* __restrict__ A,
                                                    const float* __restrict__ W,
                                                    const float* __restrict__ bias,
                                                    float* __restrict__ C, int K) {
  __shared__ short Al[BM * LDP];
  __shared__ short Bl[BN * LDP];
  const int t = threadIdx.x;
  const int m0 = blockIdx.x * BM;
  const int n0 = blockIdx.y * BN;
  const int lane = t & 63, wave = t >> 6;
  const int wm = wave >> 1, wn = wave & 1;   // 2x2 wave grid; wave tile 64x32
  const int lr = lane & 15, kg = lane >> 4;

  f32x4 acc[4][2];
#pragma unroll
  for (int i = 0; i < 4; ++i)
#pragma unroll
    for (int j = 0; j < 2; ++j) acc[i][j] = (f32x4)0.0f;

  const int nkt = K / BK;
  for (int kt = 0; kt < nkt; ++kt) {
    // stage tiles: A = 1024 f32x4 slots (128x32), B = 512 slots (64x32); convert f32->bf16
#pragma unroll
    for (int s = t; s < 1536; s += 256) {
      if (s < 1024) {
        int r = s >> 3, c4 = s & 7;
        f32x4 v = *(const f32x4*)(A + (size_t)(m0 + r) * K + kt * BK + c4 * 4);
        u16x4 h = {f2bf(v.x), f2bf(v.y), f2bf(v.z), f2bf(v.w)};
        *(u16x4*)&Al[r * LDP + c4 * 4] = h;
      } else {
        int s2 = s - 1024;
        int r = s2 >> 3, c4 = s2 & 7;
        f32x4 v = *(const f32x4*)(W + (size_t)(n0 + r) * K + kt * BK + c4 * 4);
        u16x4 h = {f2bf(v.x), f2bf(v.y), f2bf(v.z), f2bf(v.w)};
        *(u16x4*)&Bl[r * LDP + c4 * 4] = h;
      }
    }
    __syncthreads();

    bf16x8 a[4], b[2];
#pragma unroll
    for (int i = 0; i < 4; ++i)
      a[i] = *(const bf16x8*)&Al[(wm * 64 + i * 16 + lr) * LDP + kg * 8];
#pragma unroll
    for (int j = 0; j < 2; ++j)
      b[j] = *(const bf16x8*)&Bl[(wn * 32 + j * 16 + lr) * LDP + kg * 8];
#pragma unroll
    for (int i = 0; i < 4; ++i)
#pragma unroll
      for (int j = 0; j < 2; ++j)
        acc[i][j] = __builtin_amdgcn_mfma_f32_16x16x32_bf16(a[i], b[j], acc[i][j], 0, 0, 0);
    __syncthreads();
  }

  // epilogue: C/D layout col=lane&15, row=(lane>>4)*4+reg  [m89/m91-verified]
#pragma unroll
  for (int i = 0; i < 4; ++i) {
#pragma unroll
    for (int j = 0; j < 2; ++j) {
      int gcol = n0 + wn * 32 + j * 16 + lr;
      float bv = bias[gcol];
#pragma unroll
      for (int q = 0; q < 4; ++q) {
        int grow = m0 + wm * 64 + i * 16 + kg * 4 + q;
        C[(size_t)grow * HIDDEN + gcol] = acc[i][j][q] + bv;
      }
    }
  }
}

// ---------------- kernel D: sub_obj_preds + input_ggnn broadcast/gather ----------------
__global__ __launch_bounds__(256) void scatter_kernel(const int* __restrict__ rel_inds,
                                                      const float* __restrict__ obj_h,
                                                      const float* __restrict__ vr_h,
                                                      float* __restrict__ out) {
  const int r = blockIdx.x;
  const int s = rel_inds[r * 3 + 1];
  const int o = rel_inds[r * 3 + 2];
  const int t = threadIdx.x;
  if (t == 0) out[OFF_SOP + r * 2 + 0] = out[OFF_PREDS + s];
  if (t == 1) out[OFF_SOP + r * 2 + 1] = out[OFF_PREDS + o];

  const int c4 = t & 127;   // 128 float4 per 512-wide row
  const int half = t >> 7;  // 2 row-groups
  f32x4 vs = *(const f32x4*)(obj_h + (size_t)s * HIDDEN + c4 * 4);
  f32x4 vo = *(const f32x4*)(obj_h + (size_t)o * HIDDEN + c4 * 4);
  f32x4 vv = *(const f32x4*)(vr_h + (size_t)r * HIDDEN + c4 * 4);
  f32x4* o4 = (f32x4*)(out + OFF_GGNN + (size_t)r * (2 + NUM_REL_CLS) * HIDDEN);
  for (int row = half; row < 2 + NUM_REL_CLS; row += 2) {
    f32x4 val = (row == 0) ? vs : ((row == 1) ? vo : vv);
    o4[row * 128 + c4] = val;
  }
}

extern "C" void kernel_launch(void* const* d_in, const int* in_sizes, int n_in,
                              void* d_out, int out_size, void* d_ws, size_t ws_size,
                              hipStream_t stream) {
  const float* obj_fmaps  = (const float*)d_in[0];
  const float* obj_logits = (const float*)d_in[1];
  const int*   rel_inds   = (const int*)d_in[2];
  const float* vr         = (const float*)d_in[3];
  const float* Wo         = (const float*)d_in[4];
  const float* bo         = (const float*)d_in[5];
  const float* Wr         = (const float*)d_in[6];
  const float* br         = (const float*)d_in[7];
  float* out = (float*)d_out;

  float* obj_h = (float*)d_ws;                   // 256*512 f32 = 512 KB
  float* vr_h  = obj_h + NUM_OBJ * HIDDEN;       // 4096*512 f32 = 8 MB

  preds_kernel<<<NUM_OBJ, 64, 0, stream>>>(obj_logits, out);
  gemm_bt_bias<<<dim3(NUM_OBJ / BM, HIDDEN / BN), 256, 0, stream>>>(obj_fmaps, Wo, bo, obj_h, OBJ_DIM);
  gemm_bt_bias<<<dim3(NUM_REL / BM, HIDDEN / BN), 256, 0, stream>>>(vr, Wr, br, vr_h, REL_DIM);
  scatter_kernel<<<NUM_REL, 256, 0, stream>>>(rel_inds, obj_h, vr_h, out);
}

// Round 2
// 158.095 us; speedup vs baseline: 5.1950x; 5.1950x over previous
//
#include <hip/hip_runtime.h>

#define NUM_OBJ 256
#define NUM_REL 4096
#define OBJ_DIM 4096
#define REL_DIM 4096
#define HIDDEN 512
#define NUM_OBJ_CLS 151
#define NUM_REL_CLS 51

#define OFF_PREDS (NUM_OBJ * NUM_OBJ_CLS)        // 38656
#define OFF_SOP   (OFF_PREDS + NUM_OBJ)          // 38912
#define OFF_GGNN  (OFF_SOP + NUM_REL * 2)        // 47104

#define M_TOT (NUM_OBJ + NUM_REL)                // 4352
#define KDIM  4096

typedef __attribute__((ext_vector_type(4))) float          f32x4;
typedef __attribute__((ext_vector_type(8))) short          bf16x8;
typedef __attribute__((ext_vector_type(4))) unsigned short u16x4;

__device__ __forceinline__ unsigned short f2bf(float f) {
  unsigned int u = __float_as_uint(f);
  u += 0x7FFFu + ((u >> 16) & 1u);   // round-to-nearest-even
  return (unsigned short)(u >> 16);
}

__device__ __forceinline__ void gload16(const short* g, short* l) {
  __builtin_amdgcn_global_load_lds(
      (const __attribute__((address_space(1))) unsigned int*)g,
      (__attribute__((address_space(3))) unsigned int*)l, 16, 0, 0);
}

// ---------------- kernel A: logits copy + argmax(preds) ----------------
__global__ __launch_bounds__(64) void preds_kernel(const float* __restrict__ logits,
                                                   float* __restrict__ out) {
  const int row = blockIdx.x;
  const int lane = threadIdx.x;
  const float* lrow = logits + row * NUM_OBJ_CLS;
  float best = -3.0e38f;
  int bidx = NUM_OBJ_CLS;
  for (int j = lane; j < NUM_OBJ_CLS; j += 64) {
    float v = lrow[j];
    out[row * NUM_OBJ_CLS + j] = v;
    if (j >= 1 && v > best) { best = v; bidx = j; }
  }
  for (int off = 1; off < 64; off <<= 1) {
    float ob = __shfl_xor(best, off);
    int   oi = __shfl_xor(bidx, off);
    if (ob > best || (ob == best && oi < bidx)) { best = ob; bidx = oi; }
  }
  if (lane == 0) out[OFF_PREDS + row] = (float)bidx;
}

// ---------------- convert: f32 -> bf16 staging of A_cat and W_cat ----------------
__global__ __launch_bounds__(256) void convert_kernel(const float* __restrict__ obj_fmaps,
                                                      const float* __restrict__ vr,
                                                      const float* __restrict__ Wo,
                                                      const float* __restrict__ Wr,
                                                      short* __restrict__ A_bf,
                                                      short* __restrict__ W_bf) {
  const int NA = M_TOT * (KDIM / 4);   // 4,456,448 float4 groups
  const int NW = 1024 * (KDIM / 4);    // 1,048,576
  for (int i = blockIdx.x * 256 + threadIdx.x; i < NA + NW; i += gridDim.x * 256) {
    const float* src;
    short* dst;
    if (i < NA) {
      int row = i >> 10, c = i & 1023;
      src = (row < NUM_OBJ ? obj_fmaps + ((size_t)row << 12)
                           : vr + ((size_t)(row - NUM_OBJ) << 12)) + c * 4;
      dst = A_bf + ((size_t)row << 12) + c * 4;
    } else {
      int j = i - NA;
      int row = j >> 10, c = j & 1023;
      src = (row < HIDDEN ? Wo + ((size_t)row << 12)
                          : Wr + ((size_t)(row - HIDDEN) << 12)) + c * 4;
      dst = W_bf + ((size_t)row << 12) + c * 4;
    }
    f32x4 v = *(const f32x4*)src;
    u16x4 h = {f2bf(v.x), f2bf(v.y), f2bf(v.z), f2bf(v.w)};
    *(u16x4*)dst = h;
  }
}

// ---------------- fused GEMM: H[4352][512] = A_cat @ Wsel^T + bias ----------------
// 64x64 tile, BK=64, double-buffered LDS via global_load_lds(16B),
// XOR-swizzle (elem ^= (row&7)<<3) applied to global SOURCE + ds_read (rule #21).
#define GBK 64
#define GNKT (KDIM / GBK)   // 64

__global__ __launch_bounds__(256) void gemm_bf16(const short* __restrict__ A_bf,
                                                 const short* __restrict__ W_bf,
                                                 const float* __restrict__ bo,
                                                 const float* __restrict__ br,
                                                 float* __restrict__ H) {
  __shared__ short lds[2][2][64 * 64];   // [buf][A|B][4096 bf16] = 32 KiB
  const int mb = blockIdx.x, nb = blockIdx.y;
  const int m0 = mb * 64, n0 = nb * 64;
  const short* Asrc = A_bf + (size_t)m0 * KDIM;
  const short* Bsrc = W_bf + (mb < 4 ? 0 : (size_t)HIDDEN * KDIM) + (size_t)n0 * KDIM;
  const float* bias = (mb < 4) ? bo : br;

  const int t = threadIdx.x, lane = t & 63, w = t >> 6;
  const int wm = w >> 1, wn = w & 1, lr = lane & 15, kg = lane >> 4;

  // staging address precompute: LDS dest byte d = w*2048 + c*1024 + lane*16 (linear);
  // global source column pre-swizzled so that swizzled ds_read returns logical data.
  int rowS[2], colS[2];
#pragma unroll
  for (int c = 0; c < 2; ++c) {
    int row = w * 16 + c * 8 + (lane >> 3);
    rowS[c] = row;
    colS[c] = ((lane & 7) * 8) ^ ((row & 7) << 3);   // in bf16 elems
  }

  f32x4 acc[2][2];
#pragma unroll
  for (int i = 0; i < 2; ++i)
#pragma unroll
    for (int j = 0; j < 2; ++j) acc[i][j] = (f32x4)0.0f;

#define STAGE(buf, kt)                                                              \
  {                                                                                 \
    _Pragma("unroll")                                                               \
    for (int c = 0; c < 2; ++c) {                                                   \
      gload16(Asrc + (size_t)rowS[c] * KDIM + (kt) * GBK + colS[c],                 \
              &lds[buf][0][w * 1024 + c * 512]);                                    \
      gload16(Bsrc + (size_t)rowS[c] * KDIM + (kt) * GBK + colS[c],                 \
              &lds[buf][1][w * 1024 + c * 512]);                                    \
    }                                                                               \
  }

  STAGE(0, 0);
  __syncthreads();

  int cur = 0;
  for (int kt = 0; kt < GNKT; ++kt) {
    if (kt + 1 < GNKT) STAGE(cur ^ 1, kt + 1);

    bf16x8 a[2][2], b[2][2];
#pragma unroll
    for (int i = 0; i < 2; ++i) {
      int r = wm * 32 + i * 16 + lr;
      int sw = (r & 7) << 3;
#pragma unroll
      for (int ks = 0; ks < 2; ++ks)
        a[i][ks] = *(const bf16x8*)&lds[cur][0][r * 64 + ((ks * 32 + kg * 8) ^ sw)];
    }
#pragma unroll
    for (int j = 0; j < 2; ++j) {
      int r = wn * 32 + j * 16 + lr;
      int sw = (r & 7) << 3;
#pragma unroll
      for (int ks = 0; ks < 2; ++ks)
        b[j][ks] = *(const bf16x8*)&lds[cur][1][r * 64 + ((ks * 32 + kg * 8) ^ sw)];
    }

#pragma unroll
    for (int ks = 0; ks < 2; ++ks)
#pragma unroll
      for (int i = 0; i < 2; ++i)
#pragma unroll
        for (int j = 0; j < 2; ++j)
          acc[i][j] = __builtin_amdgcn_mfma_f32_16x16x32_bf16(a[i][ks], b[j][ks], acc[i][j], 0, 0, 0);

    __syncthreads();
    cur ^= 1;
  }

  // epilogue: C/D layout col=lane&15, row=(lane>>4)*4+reg
#pragma unroll
  for (int i = 0; i < 2; ++i) {
#pragma unroll
    for (int j = 0; j < 2; ++j) {
      int gcol = n0 + wn * 32 + j * 16 + lr;
      float bv = bias[gcol];
#pragma unroll
      for (int q = 0; q < 4; ++q) {
        int grow = m0 + wm * 32 + i * 16 + kg * 4 + q;
        H[(size_t)grow * HIDDEN + gcol] = acc[i][j][q] + bv;
      }
    }
  }
#undef STAGE
}

// ---------------- fallback GEMM (round-1 path, used only if ws too small) ----------------
#define BM 128
#define BN 64
#define BK 32
#define LDP 40

__global__ __launch_bounds__(256) void gemm_bt_bias(const float* __restrict__ A,
                                                    const float* __restrict__ W,
                                                    const float* __restrict__ bias,
                                                    float* __restrict__ C, int K) {
  __shared__ short Al[BM * LDP];
  __shared__ short Bl[BN * LDP];
  const int t = threadIdx.x;
  const int m0 = blockIdx.x * BM;
  const int n0 = blockIdx.y * BN;
  const int lane = t & 63, wave = t >> 6;
  const int wm = wave >> 1, wn = wave & 1;
  const int lr = lane & 15, kg = lane >> 4;

  f32x4 acc[4][2];
#pragma unroll
  for (int i = 0; i < 4; ++i)
#pragma unroll
    for (int j = 0; j < 2; ++j) acc[i][j] = (f32x4)0.0f;

  const int nkt = K / BK;
  for (int kt = 0; kt < nkt; ++kt) {
#pragma unroll
    for (int s = t; s < 1536; s += 256) {
      if (s < 1024) {
        int r = s >> 3, c4 = s & 7;
        f32x4 v = *(const f32x4*)(A + (size_t)(m0 + r) * K + kt * BK + c4 * 4);
        u16x4 h = {f2bf(v.x), f2bf(v.y), f2bf(v.z), f2bf(v.w)};
        *(u16x4*)&Al[r * LDP + c4 * 4] = h;
      } else {
        int s2 = s - 1024;
        int r = s2 >> 3, c4 = s2 & 7;
        f32x4 v = *(const f32x4*)(W + (size_t)(n0 + r) * K + kt * BK + c4 * 4);
        u16x4 h = {f2bf(v.x), f2bf(v.y), f2bf(v.z), f2bf(v.w)};
        *(u16x4*)&Bl[r * LDP + c4 * 4] = h;
      }
    }
    __syncthreads();

    bf16x8 a[4], b[2];
#pragma unroll
    for (int i = 0; i < 4; ++i)
      a[i] = *(const bf16x8*)&Al[(wm * 64 + i * 16 + lr) * LDP + kg * 8];
#pragma unroll
    for (int j = 0; j < 2; ++j)
      b[j] = *(const bf16x8*)&Bl[(wn * 32 + j * 16 + lr) * LDP + kg * 8];
#pragma unroll
    for (int i = 0; i < 4; ++i)
#pragma unroll
      for (int j = 0; j < 2; ++j)
        acc[i][j] = __builtin_amdgcn_mfma_f32_16x16x32_bf16(a[i], b[j], acc[i][j], 0, 0, 0);
    __syncthreads();
  }

#pragma unroll
  for (int i = 0; i < 4; ++i) {
#pragma unroll
    for (int j = 0; j < 2; ++j) {
      int gcol = n0 + wn * 32 + j * 16 + lr;
      float bv = bias[gcol];
#pragma unroll
      for (int q = 0; q < 4; ++q) {
        int grow = m0 + wm * 64 + i * 16 + kg * 4 + q;
        C[(size_t)grow * HIDDEN + gcol] = acc[i][j][q] + bv;
      }
    }
  }
}

// ---------------- scatter: sub_obj_preds + input_ggnn ----------------
__global__ __launch_bounds__(256) void scatter_kernel(const int* __restrict__ rel_inds,
                                                      const float* __restrict__ obj_h,
                                                      const float* __restrict__ vr_h,
                                                      float* __restrict__ out) {
  const int r = blockIdx.x;
  const int s = rel_inds[r * 3 + 1];
  const int o = rel_inds[r * 3 + 2];
  const int t = threadIdx.x;
  if (t == 0) out[OFF_SOP + r * 2 + 0] = out[OFF_PREDS + s];
  if (t == 1) out[OFF_SOP + r * 2 + 1] = out[OFF_PREDS + o];

  const int c4 = t & 127;
  const int half = t >> 7;
  f32x4 vs = *(const f32x4*)(obj_h + (size_t)s * HIDDEN + c4 * 4);
  f32x4 vo = *(const f32x4*)(obj_h + (size_t)o * HIDDEN + c4 * 4);
  f32x4 vv = *(const f32x4*)(vr_h + (size_t)r * HIDDEN + c4 * 4);
  f32x4* o4 = (f32x4*)(out + OFF_GGNN + (size_t)r * (2 + NUM_REL_CLS) * HIDDEN);
  for (int row = half; row < 2 + NUM_REL_CLS; row += 2) {
    f32x4 val = (row == 0) ? vs : ((row == 1) ? vo : vv);
    o4[row * 128 + c4] = val;
  }
}

extern "C" void kernel_launch(void* const* d_in, const int* in_sizes, int n_in,
                              void* d_out, int out_size, void* d_ws, size_t ws_size,
                              hipStream_t stream) {
  const float* obj_fmaps  = (const float*)d_in[0];
  const float* obj_logits = (const float*)d_in[1];
  const int*   rel_inds   = (const int*)d_in[2];
  const float* vr         = (const float*)d_in[3];
  const float* Wo         = (const float*)d_in[4];
  const float* bo         = (const float*)d_in[5];
  const float* Wr         = (const float*)d_in[6];
  const float* br         = (const float*)d_in[7];
  float* out = (float*)d_out;

  const size_t H_BYTES = (size_t)M_TOT * HIDDEN * 4;          // 8,912,896
  const size_t A_BYTES = (size_t)M_TOT * KDIM * 2;            // 35,651,584
  const size_t W_BYTES = (size_t)1024 * KDIM * 2;             // 8,388,608

  preds_kernel<<<NUM_OBJ, 64, 0, stream>>>(obj_logits, out);

  if (ws_size >= H_BYTES + A_BYTES + W_BYTES) {
    float* H    = (float*)d_ws;
    float* obj_h = H;
    float* vr_h  = H + (size_t)NUM_OBJ * HIDDEN;
    short* A_bf = (short*)((char*)d_ws + H_BYTES);
    short* W_bf = (short*)((char*)d_ws + H_BYTES + A_BYTES);

    convert_kernel<<<2048, 256, 0, stream>>>(obj_fmaps, vr, Wo, Wr, A_bf, W_bf);
    gemm_bf16<<<dim3(M_TOT / 64, HIDDEN / 64), 256, 0, stream>>>(A_bf, W_bf, bo, br, H);
    scatter_kernel<<<NUM_REL, 256, 0, stream>>>(rel_inds, obj_h, vr_h, out);
  } else {
    float* obj_h = (float*)d_ws;
    float* vr_h  = obj_h + NUM_OBJ * HIDDEN;
    gemm_bt_bias<<<dim3(NUM_OBJ / BM, HIDDEN / BN), 256, 0, stream>>>(obj_fmaps, Wo, bo, obj_h, OBJ_DIM);
    gemm_bt_bias<<<dim3(NUM_REL / BM, HIDDEN / BN), 256, 0, stream>>>(vr, Wr, br, vr_h, REL_DIM);
    scatter_kernel<<<NUM_REL, 256, 0, stream>>>(rel_inds, obj_h, vr_h, out);
  }
}